// Round 10
// baseline (447.786 us; speedup 1.0000x reference)
//
#include <hip/hip_runtime.h>

// Cross product along dim=1 of (16, 3, 1024, 1024) fp32 tensors.
// idx = ((b*3 + c)*1024 + h)*1024 + w; plane = 4MiB; batch = 3 planes.
//
// Measured history (kernel-level, CU-side delivered bytes / dur):
//  r4  grid-stride all-nt:        604MB / 122.3us = 4.95 TB/s  FETCH 197MB
//  r5  c-split (2x reads):       1006MB / 188us   = 5.35 TB/s  FETCH 402MB
//  r6  contiguous+mixed policy:   604MB / 165us   = 3.66 TB/s  REGRESSION
//  r7  4x unroll (intent: 24 loads in flight): 122.1us, VGPR=32 -> compiler
//      SANK the loads back to uses; the MLP experiment never ran at ISA level.
//  harness fills keep ~200MB of inputs cache-resident every iteration
//  (FETCH pinned at 197MB in r4/r6 under opposite cache policies).
//
// r10: r7 done right. All 24 nt loads issued, then sched_barrier(0) —
// nothing may cross — then compute+stores. Forces ~96 data VGPRs live
// (profile VGPR_Count self-verifies). launch_bounds(256,4) holds VGPR<=128
// -> 4 waves/SIMD = 16/CU, occupancy unchanged vs r4. Single variable:
// per-wave outstanding load bytes (192B -> 384B).

typedef float vf4 __attribute__((ext_vector_type(4)));

#define P4 (1024 * 1024 / 4)   // float4 elements per component plane (262144, pow2)

#define NTL(p)    __builtin_nontemporal_load(p)
#define NTS(v, p) __builtin_nontemporal_store((v), (p))

__device__ __forceinline__ long plane_base(int i) {
    // i in [0, 16*P4): batch = i / P4, r = i % P4
    return (long)(i >> 18) * (3 * P4) + (i & (P4 - 1));
}

__global__ __launch_bounds__(256, 4) void cross_kernel(
    const vf4* __restrict__ a,
    const vf4* __restrict__ b,
    vf4* __restrict__ out,
    int n4)   // total float4 positions = 16 * P4 = 4,194,304
{
    const int nth = gridDim.x * blockDim.x;   // 524,288
    int i = blockIdx.x * blockDim.x + threadIdx.x;

    // Two quad-iterations: n4 = 8 * nth exactly (tail kept for safety).
    for (; i + 3 * nth < n4; i += 4 * nth) {
        long pp[4];
        vf4 A0[4], A1[4], A2[4], B0[4], B1[4], B2[4];
#pragma unroll
        for (int u = 0; u < 4; ++u) {
            pp[u] = plane_base(i + u * nth);
            A0[u] = NTL(a + pp[u]);
            A1[u] = NTL(a + pp[u] + P4);
            A2[u] = NTL(a + pp[u] + 2 * P4);
            B0[u] = NTL(b + pp[u]);
            B1[u] = NTL(b + pp[u] + P4);
            B2[u] = NTL(b + pp[u] + 2 * P4);
        }
        // Hard scheduling fence: loads above may NOT be sunk below this
        // point; computes/stores may not be hoisted above it. This is what
        // r7 was missing — the compiler folded the load cluster away.
        __builtin_amdgcn_sched_barrier(0);
#pragma unroll
        for (int u = 0; u < 4; ++u) {
            NTS(A1[u] * B2[u] - A2[u] * B1[u], out + pp[u]);
            NTS(A2[u] * B0[u] - A0[u] * B2[u], out + pp[u] + P4);
            NTS(A0[u] * B1[u] - A1[u] * B0[u], out + pp[u] + 2 * P4);
        }
    }

    // Tail (dead for this shape, kept for safety): one position at a time.
    for (; i < n4; i += nth) {
        const long p = plane_base(i);
        vf4 a0 = NTL(a + p), a1 = NTL(a + p + P4), a2 = NTL(a + p + 2 * P4);
        vf4 b0 = NTL(b + p), b1 = NTL(b + p + P4), b2 = NTL(b + p + 2 * P4);
        NTS(a1 * b2 - a2 * b1, out + p);
        NTS(a2 * b0 - a0 * b2, out + p + P4);
        NTS(a0 * b1 - a1 * b0, out + p + 2 * P4);
    }
}

extern "C" void kernel_launch(void* const* d_in, const int* in_sizes, int n_in,
                              void* d_out, int out_size, void* d_ws, size_t ws_size,
                              hipStream_t stream) {
    const vf4* a = (const vf4*)d_in[0];
    const vf4* b = (const vf4*)d_in[1];
    vf4* out = (vf4*)d_out;

    int n4 = out_size / 3 / 4;   // 4,194,304
    int block = 256;
    // 8 positions per thread -> 2048 blocks (8 blocks/CU), 2 quad-iterations.
    int grid = (n4 + block * 8 - 1) / (block * 8);
    cross_kernel<<<grid, block, 0, stream>>>(a, b, out, n4);
}